// Round 4
// baseline (762.542 us; speedup 1.0000x reference)
//
#include <hip/hip_runtime.h>
#include <hip/hip_bf16.h>

typedef __bf16 bf16x8 __attribute__((ext_vector_type(8)));
typedef __bf16 bf16x4 __attribute__((ext_vector_type(4)));
typedef float  f32x4  __attribute__((ext_vector_type(4)));

#define MFMA16(a, b, c) __builtin_amdgcn_mfma_f32_16x16x32_bf16((a), (b), (c), 0, 0, 0)

// ---------------------------------------------------------------------------
// K1: block 240: exclusive scan of sizes (+ total at offsets[8192]);
// blocks 0-47: conv weight pack; 48-239: lin_w hi/lo pack;
// 241-1008: zero-init Pool (8192*384 uint = relu floor / atomicMax identity).
// B-frag for 16x16x32: lane holds B[k = (lane>>4)*8 + j][n = lane&15], j=0..7.
// ---------------------------------------------------------------------------
__global__ void k_prep(const int* __restrict__ sizes, int* __restrict__ offsets,
                       const float* __restrict__ w0, const float* __restrict__ w1,
                       const float* __restrict__ w2, const float* __restrict__ lw,
                       __bf16* __restrict__ Wpack,
                       __bf16* __restrict__ Lhi, __bf16* __restrict__ Llo,
                       unsigned* __restrict__ Pool) {
  const int bid = blockIdx.x, t = threadIdx.x;
  if (bid == 240) {
    __shared__ int part[256];
    const int base = t * 32;
    int v[32];
    int s = 0;
#pragma unroll
    for (int i = 0; i < 32; ++i) { v[i] = sizes[base + i]; s += v[i]; }
    part[t] = s;
    __syncthreads();
    for (int d = 1; d < 256; d <<= 1) {
      int add = (t >= d) ? part[t - d] : 0;
      __syncthreads();
      part[t] += add;
      __syncthreads();
    }
    int run = (t == 0) ? 0 : part[t - 1];
#pragma unroll
    for (int i = 0; i < 32; ++i) { offsets[base + i] = run; run += v[i]; }
    if (t == 255) offsets[8192] = run;    // total token count T
  } else if (bid < 48) {
    const int nt = bid, sl = nt >> 3, f = nt & 7;
    const int kt = t >> 6, lane = t & 63;
    const float* src; int kw, jj;
    if      (sl == 0) { src = w0; kw = 1; jj = 0; }
    else if (sl == 1) { src = w1; kw = 2; jj = 0; }
    else if (sl == 2) { src = w1; kw = 2; jj = 1; }
    else if (sl == 3) { src = w2; kw = 3; jj = 0; }
    else if (sl == 4) { src = w2; kw = 3; jj = 1; }
    else              { src = w2; kw = 3; jj = 2; }
    const int feat  = f * 16 + (lane & 15);
    const int cbase = kt * 32 + ((lane >> 4) << 3);
    __bf16* dst = Wpack + ((((nt * 4 + kt) << 6) + lane) << 3);
#pragma unroll
    for (int j = 0; j < 8; ++j)
      dst[j] = (__bf16)src[(feat * 128 + cbase + j) * kw + jj];
  } else if (bid < 240) {
    const int idx = (bid - 48) * 256 + t;          // 0..49151
    const int j = idx & 7, lane = (idx >> 3) & 63, rest = idx >> 9;  // 0..95
    const int kt = rest % 12, nt = rest / 12;
    const int o = nt * 16 + (lane & 15);
    const int q = kt * 32 + ((lane >> 4) << 3) + j;
    const float v = lw[o * 384 + q];
    const __bf16 hi = (__bf16)v;
    Lhi[idx] = hi;
    Llo[idx] = (__bf16)(v - (float)hi);
  } else {
    // bid 241..1008: 768 blocks x 256 threads x 4 int4 = 3,145,728 words
    int4* p = (int4*)Pool + ((bid - 241) * 1024 + t * 4);
    const int4 z{0, 0, 0, 0};
    p[0] = z; p[1] = z; p[2] = z; p[3] = z;
  }
}

// ---------------------------------------------------------------------------
// K2 v4: DENSE persistent GEMM + atomic ragged max.
// 1024 blocks x 256 threads; block b sweeps a contiguous chunk of 64-row
// tiles (~5 tiles).  Per tile: stage 66 rows (2-row tap overlap) into
// double-buffered LDS, 8 ft-tiles x 4 mt x 4 kt MFMAs (no raggedness, no
// padding waste), then a per-lane epilogue: walk own 16 rows in order with
// an incremental segment pointer (offsets L2-hot; row jumps <=13 < min seg
// 16), keep running relu'd max per pool, atomicMax(uint) flush on segment
// crossing.  relu'd values are >=0 so float bits are monotone as uints and
// zero-init == identity.  No per-segment barriers, no shuffles, no stores.
// C/D layout (m89-verified): col = lane&15, row = (lane>>4)*4 + reg.
// ---------------------------------------------------------------------------
__global__ __launch_bounds__(256, 3)
void k_conv(const float* __restrict__ x, const int* __restrict__ offsets,
            const float* __restrict__ cb0, const float* __restrict__ cb1,
            const float* __restrict__ cb2,
            const bf16x8* __restrict__ Wpack,
            unsigned* __restrict__ Pool) {
  __shared__ __align__(16) __bf16 xs[2][66 * 136];   // 2 x 17.95 KB
  const int t = threadIdx.x;
  const int wid = t >> 6, lane = t & 63;
  const int lo16 = lane & 15, g16 = lane >> 4;
  const int T = offsets[8192];
  const int ntiles = (T + 63) >> 6;
  const int per = (ntiles + 1023) >> 10;
  const int t0 = blockIdx.x * per;
  const int t1 = min(t0 + per, ntiles);
  if (t0 >= t1) return;

  const int feat0 = wid * 16 + lo16, feat1 = feat0 + 64;
  const float cbv[2][3] = {{cb0[feat0], cb1[feat0], cb2[feat0]},
                           {cb0[feat1], cb1[feat1], cb2[feat1]}};

  // init lane's segment pointer for its first epilogue row
  int seg, end;
  {
    const int r0 = t0 * 64 + (g16 << 2);
    int lo = 0, hi = 8192;
    while (hi - lo > 1) {
      const int mid = (lo + hi) >> 1;
      if (offsets[mid] <= r0) lo = mid; else hi = mid;
    }
    seg = lo; end = offsets[seg + 1];
  }
  float pm[2][3] = {{0.f, 0.f, 0.f}, {0.f, 0.f, 0.f}};  // relu floor

  // ---- prologue: stage tile t0 into xs[0] (66 rows, predicated by T) ----
  {
    const long tb = (long)t0 * 64;
    float4 pa[5], pb[5]; bool pact[5];
#pragma unroll
    for (int k = 0; k < 5; ++k) {
      const int u = t + (k << 8);
      pact[k] = (k < 4 || t < 32) && (tb + (u >> 4) < T);
      if (pact[k]) {
        const float* p = x + (tb + (u >> 4)) * 128 + ((u & 15) << 3);
        pa[k] = *(const float4*)p; pb[k] = *(const float4*)(p + 4);
      }
    }
#pragma unroll
    for (int k = 0; k < 5; ++k) if (pact[k]) {
      const int u = t + (k << 8);
      bf16x8 h;
      h[0]=(__bf16)pa[k].x; h[1]=(__bf16)pa[k].y; h[2]=(__bf16)pa[k].z; h[3]=(__bf16)pa[k].w;
      h[4]=(__bf16)pb[k].x; h[5]=(__bf16)pb[k].y; h[6]=(__bf16)pb[k].z; h[7]=(__bf16)pb[k].w;
      *(bf16x8*)&xs[0][(u >> 4) * 136 + ((u & 15) << 3)] = h;
    }
  }
  __syncthreads();

  int cur = 0;
  for (int tt = t0; tt < t1; ++tt) {
    const long tb = (long)tt * 64;
    const bool hasNext = (tt + 1 < t1);

    // ---- phase A: issue next tile's loads (regs only; land under MFMAs) ----
    float4 va[5], vb[5]; bool act[5] = {false, false, false, false, false};
    if (hasNext) {
      const long nb = tb + 64;
#pragma unroll
      for (int k = 0; k < 5; ++k) {
        const int u = t + (k << 8);
        act[k] = (k < 4 || t < 32) && (nb + (u >> 4) < T);
        if (act[k]) {
          const float* p = x + (nb + (u >> 4)) * 128 + ((u & 15) << 3);
          va[k] = *(const float4*)p; vb[k] = *(const float4*)(p + 4);
        }
      }
    }

    // ---- phase B + epilogue, per feature half ----
    const __bf16* xb = xs[cur];
    const int sg0 = seg, en0 = end;
#pragma unroll
    for (int fi = 0; fi < 2; ++fi) {
      const int ft = wid + (fi << 2);
      f32x4 acc[4][3];
#pragma unroll
      for (int mt = 0; mt < 4; ++mt)
#pragma unroll
        for (int p = 0; p < 3; ++p) acc[mt][p] = f32x4{0.f, 0.f, 0.f, 0.f};
#pragma unroll
      for (int kt = 0; kt < 4; ++kt) {
        bf16x8 bf[6];   // 0=w1j0, 1=w2j0, 2=w2j1, 3=w3j0, 4=w3j1, 5=w3j2
#pragma unroll
        for (int sl = 0; sl < 6; ++sl)
          bf[sl] = Wpack[(((sl * 8 + ft) * 4 + kt) << 6) + lane];
#pragma unroll
        for (int mt = 0; mt < 4; ++mt) {
          const __bf16* ap = &xb[(mt * 16 + lo16) * 136 + kt * 32 + (g16 << 3)];
          const bf16x8 A0 = *(const bf16x8*)ap;
          const bf16x8 A1 = *(const bf16x8*)(ap + 136);
          const bf16x8 A2 = *(const bf16x8*)(ap + 272);
          acc[mt][0] = MFMA16(A0, bf[0], acc[mt][0]);
          acc[mt][1] = MFMA16(A0, bf[1], acc[mt][1]);
          acc[mt][1] = MFMA16(A1, bf[2], acc[mt][1]);
          acc[mt][2] = MFMA16(A0, bf[3], acc[mt][2]);
          acc[mt][2] = MFMA16(A1, bf[4], acc[mt][2]);
          acc[mt][2] = MFMA16(A2, bf[5], acc[mt][2]);
        }
      }
      // ---- epilogue: run-length max with incremental seg walk ----
      const int feat = fi ? feat1 : feat0;
      int sg = sg0, en = en0;
#pragma unroll
      for (int mt = 0; mt < 4; ++mt)
#pragma unroll
        for (int v = 0; v < 4; ++v) {
          const int r = (int)tb + mt * 16 + (g16 << 2) + v;
          if (r < T) {
            if (r >= en) {
              unsigned* bp = Pool + (long)sg * 384 + feat;
              atomicMax(bp,       __float_as_uint(pm[fi][0]));
              atomicMax(bp + 128, __float_as_uint(pm[fi][1]));
              atomicMax(bp + 256, __float_as_uint(pm[fi][2]));
              pm[fi][0] = pm[fi][1] = pm[fi][2] = 0.f;
              do { ++sg; en = offsets[sg + 1]; } while (r >= en);
            }
            pm[fi][0] = fmaxf(pm[fi][0], acc[mt][0][v] + cbv[fi][0]);
            if (r + 1 < en) pm[fi][1] = fmaxf(pm[fi][1], acc[mt][1][v] + cbv[fi][1]);
            if (r + 2 < en) pm[fi][2] = fmaxf(pm[fi][2], acc[mt][2][v] + cbv[fi][2]);
          }
        }
      if (fi == 1) { seg = sg; end = en; }
    }

    // ---- phase C: convert + write next tile, one barrier per tile ----
    if (hasNext) {
#pragma unroll
      for (int k = 0; k < 5; ++k) if (act[k]) {
        const int u = t + (k << 8);
        bf16x8 h;
        h[0]=(__bf16)va[k].x; h[1]=(__bf16)va[k].y; h[2]=(__bf16)va[k].z; h[3]=(__bf16)va[k].w;
        h[4]=(__bf16)vb[k].x; h[5]=(__bf16)vb[k].y; h[6]=(__bf16)vb[k].z; h[7]=(__bf16)vb[k].w;
        *(bf16x8*)&xs[cur ^ 1][(u >> 4) * 136 + ((u & 15) << 3)] = h;
      }
      __syncthreads();
      cur ^= 1;
    }
  }

  // ---- final flush of the last open segment ----
  {
    unsigned* bp = Pool + (long)seg * 384;
    atomicMax(bp + feat0,       __float_as_uint(pm[0][0]));
    atomicMax(bp + 128 + feat0, __float_as_uint(pm[0][1]));
    atomicMax(bp + 256 + feat0, __float_as_uint(pm[0][2]));
    atomicMax(bp + feat1,       __float_as_uint(pm[1][0]));
    atomicMax(bp + 128 + feat1, __float_as_uint(pm[1][1]));
    atomicMax(bp + 256 + feat1, __float_as_uint(pm[1][2]));
  }
}

// ---------------------------------------------------------------------------
// K3 v3: out = tanh(P @ lin_w^T + lin_b), P = Pool fp32 (already relu+bias).
// Split hi/lo on the fly during staging; 3 independent MFMA chains; 1024
// blocks (16 rows x 64 feats each).
// ---------------------------------------------------------------------------
__global__ __launch_bounds__(256, 4)
void k_lin(const float* __restrict__ Pool,
           const bf16x8* __restrict__ Lhi, const bf16x8* __restrict__ Llo,
           const float* __restrict__ lb, float* __restrict__ out) {
  __shared__ __bf16 ph[16 * 392];   // [row][384 + 8 pad]
  __shared__ __bf16 pl[16 * 392];
  const int blk = blockIdx.x, t = threadIdx.x;
  const int mb = blk >> 1, nh = blk & 1;
  const long rbase = (long)mb * 16;
#pragma unroll
  for (int i = 0; i < 6; ++i) {
    const int ci = t + (i << 8);            // 0..1535 quads (16 rows x 96)
    const int r = ci / 96, c4 = ci % 96;
    const float4 v = *(const float4*)(Pool + (rbase + r) * 384 + (c4 << 2));
    bf16x4 h, l;
    h[0] = (__bf16)v.x; l[0] = (__bf16)(v.x - (float)h[0]);
    h[1] = (__bf16)v.y; l[1] = (__bf16)(v.y - (float)h[1]);
    h[2] = (__bf16)v.z; l[2] = (__bf16)(v.z - (float)h[2]);
    h[3] = (__bf16)v.w; l[3] = (__bf16)(v.w - (float)h[3]);
    *(bf16x4*)&ph[r * 392 + (c4 << 2)] = h;
    *(bf16x4*)&pl[r * 392 + (c4 << 2)] = l;
  }
  __syncthreads();
  const int wid = t >> 6, lane = t & 63;
  const int lo16 = lane & 15, g = lane >> 4;
  const int nt = (nh << 2) + wid;       // global n-tile 0..7
  f32x4 ahh = f32x4{0.f, 0.f, 0.f, 0.f};
  f32x4 alh = f32x4{0.f, 0.f, 0.f, 0.f};
  f32x4 ahl = f32x4{0.f, 0.f, 0.f, 0.f};
#pragma unroll
  for (int kt = 0; kt < 12; ++kt) {
    const bf16x8 bh = Lhi[((nt * 12 + kt) << 6) + lane];
    const bf16x8 bl = Llo[((nt * 12 + kt) << 6) + lane];
    const int aoff = lo16 * 392 + kt * 32 + (g << 3);
    const bf16x8 ah = *(const bf16x8*)&ph[aoff];
    const bf16x8 al = *(const bf16x8*)&pl[aoff];
    ahh = MFMA16(ah, bh, ahh);
    alh = MFMA16(al, bh, alh);
    ahl = MFMA16(ah, bl, ahl);
  }
  const int o = (nt << 4) + lo16;
  const float bias = lb[o];
#pragma unroll
  for (int v = 0; v < 4; ++v) {
    const int r = g * 4 + v;
    const float val = ahh[v] + alh[v] + ahl[v] + bias;
    out[(rbase + r) * 128 + o] = 1.f - 2.f / (__expf(2.f * val) + 1.f);
  }
}

// ---------------------------------------------------------------------------
extern "C" void kernel_launch(void* const* d_in, const int* in_sizes, int n_in,
                              void* d_out, int out_size, void* d_ws, size_t ws_size,
                              hipStream_t stream) {
  const float* x   = (const float*)d_in[0];
  const int* sizes = (const int*)d_in[1];
  const float* w0  = (const float*)d_in[2];
  const float* cb0 = (const float*)d_in[3];
  const float* w1  = (const float*)d_in[4];
  const float* cb1 = (const float*)d_in[5];
  const float* w2  = (const float*)d_in[6];
  const float* cb2 = (const float*)d_in[7];
  const float* lw  = (const float*)d_in[8];
  const float* lb  = (const float*)d_in[9];

  char* ws = (char*)d_ws;
  size_t o = 0;
  int*      offsets = (int*)ws;             o += 33280;        // 8193 ints
  __bf16*   Wpack   = (__bf16*)(ws + o);    o += 196608;       // 48*4*64*8*2
  __bf16*   Lhi     = (__bf16*)(ws + o);    o += 98304;        // 8*12*64*8*2
  __bf16*   Llo     = (__bf16*)(ws + o);    o += 98304;
  unsigned* Pool    = (unsigned*)(ws + o);  o += 8192L * 384 * 4;

  k_prep<<<1009, 256, 0, stream>>>(sizes, offsets, w0, w1, w2, lw,
                                   Wpack, Lhi, Llo, Pool);
  k_conv<<<1024, 256, 0, stream>>>(x, offsets, cb0, cb1, cb2,
                                   (const bf16x8*)Wpack, Pool);
  k_lin<<<1024, 256, 0, stream>>>((const float*)Pool, (const bf16x8*)Lhi,
                                  (const bf16x8*)Llo, lb, (float*)d_out);
}

// Round 7
// 307.429 us; speedup vs baseline: 2.4804x; 2.4804x over previous
//
#include <hip/hip_runtime.h>
#include <hip/hip_bf16.h>

typedef __bf16 bf16x8 __attribute__((ext_vector_type(8)));
typedef __bf16 bf16x4 __attribute__((ext_vector_type(4)));
typedef float  f32x4  __attribute__((ext_vector_type(4)));

#define MFMA16(a, b, c) __builtin_amdgcn_mfma_f32_16x16x32_bf16((a), (b), (c), 0, 0, 0)

// ---------------------------------------------------------------------------
// K1: block 240: exclusive scan of sizes -> desc[i] = {offset, size};
// blocks 0-47: conv weight pack; 48-239: lin_w hi/lo pack.
// B-frag for 16x16x32: lane holds B[k = (lane>>4)*8 + j][n = lane&15], j=0..7.
// ---------------------------------------------------------------------------
__global__ void k_prep(const int* __restrict__ sizes, int2* __restrict__ desc,
                       const float* __restrict__ w0, const float* __restrict__ w1,
                       const float* __restrict__ w2, const float* __restrict__ lw,
                       __bf16* __restrict__ Wpack,
                       __bf16* __restrict__ Lhi, __bf16* __restrict__ Llo) {
  const int bid = blockIdx.x, t = threadIdx.x;
  if (bid == 240) {
    __shared__ int part[256];
    const int base = t * 32;
    int v[32];
    int s = 0;
#pragma unroll
    for (int i = 0; i < 32; ++i) { v[i] = sizes[base + i]; s += v[i]; }
    part[t] = s;
    __syncthreads();
    for (int d = 1; d < 256; d <<= 1) {
      int add = (t >= d) ? part[t - d] : 0;
      __syncthreads();
      part[t] += add;
      __syncthreads();
    }
    int run = (t == 0) ? 0 : part[t - 1];
#pragma unroll
    for (int i = 0; i < 32; ++i) { desc[base + i] = make_int2(run, v[i]); run += v[i]; }
  } else if (bid < 48) {
    const int nt = bid, sl = nt >> 3, f = nt & 7;
    const int kt = t >> 6, lane = t & 63;
    const float* src; int kw, jj;
    if      (sl == 0) { src = w0; kw = 1; jj = 0; }
    else if (sl == 1) { src = w1; kw = 2; jj = 0; }
    else if (sl == 2) { src = w1; kw = 2; jj = 1; }
    else if (sl == 3) { src = w2; kw = 3; jj = 0; }
    else if (sl == 4) { src = w2; kw = 3; jj = 1; }
    else              { src = w2; kw = 3; jj = 2; }
    const int feat  = f * 16 + (lane & 15);
    const int cbase = kt * 32 + ((lane >> 4) << 3);
    __bf16* dst = Wpack + ((((nt * 4 + kt) << 6) + lane) << 3);
#pragma unroll
    for (int j = 0; j < 8; ++j)
      dst[j] = (__bf16)src[(feat * 128 + cbase + j) * kw + jj];
  } else {
    const int idx = (bid - 48) * 256 + t;          // 0..49151
    const int j = idx & 7, lane = (idx >> 3) & 63, rest = idx >> 9;  // 0..95
    const int kt = rest % 12, nt = rest / 12;
    const int o = nt * 16 + (lane & 15);
    const int q = kt * 32 + ((lane >> 4) << 3) + j;
    const float v = lw[o * 384 + q];
    const __bf16 hi = (__bf16)v;
    Lhi[idx] = hi;
    Llo[idx] = (__bf16)(v - (float)hi);
  }
}

// ---------------------------------------------------------------------------
// K2 v5b: fused conv+relu+ragged max with issue-count cuts.  R6 bugfix:
// pool-3 validity needs lrow <= s-3; the penultimate tile's last row can be
// s-2 (when s % 16 == 1), whose width-3 window reads the zero-padded row s.
// Tile classes: deep interior (mt+2 < MT: max row <= s-3, all pools
// unpredicated), penultimate (pools 1,2 unpredicated — max row <= s-2 —
// pool 3 per-element predicated), boundary (all predicated).
// C/D layout (m89-verified): col = lane&15, row = (lane>>4)*4 + reg.
// ---------------------------------------------------------------------------
__global__ __launch_bounds__(256, 4)
void k_conv(const float* __restrict__ x, const int2* __restrict__ desc,
            const float* __restrict__ cb0, const float* __restrict__ cb1,
            const float* __restrict__ cb2,
            const bf16x8* __restrict__ Wpack,
            __bf16* __restrict__ Phi, __bf16* __restrict__ Plo) {
  __shared__ __bf16 xh[66 * 136];   // [row][128 + 8 pad] bf16, 17.9 KB
  const int b = blockIdx.x;
  const int2 d = desc[b];
  const long off = d.x;
  const int s = d.y;
  const int t = threadIdx.x;
  const int MT = (s + 15) >> 4;     // 1..4

  // ---- two-phase staging: 8 clamped (unconditional) float4 loads, then
  // predicated convert+store.  Covers rows [0, s). ----
  {
    const int quads = s << 5;       // s*128/4
    const int qm = quads - 1;
    float4 v[8];
#pragma unroll
    for (int i = 0; i < 8; ++i) {
      const int qi = min(t + (i << 8), qm);
      const int r = qi >> 5, c = (qi & 31) << 2;
      v[i] = *(const float4*)(x + (off + r) * 128 + c);
    }
#pragma unroll
    for (int i = 0; i < 8; ++i) {
      const int qi = t + (i << 8);
      if (qi < quads) {
        const int r = qi >> 5, c = (qi & 31) << 2;
        bf16x4 h; h[0] = (__bf16)v[i].x; h[1] = (__bf16)v[i].y;
                  h[2] = (__bf16)v[i].z; h[3] = (__bf16)v[i].w;
        *(bf16x4*)&xh[r * 136 + c] = h;
      }
    }
    // zero rows [s, MT*16+2): taps read up to row MT*16+1
    const int zend = MT * 16 + 2;
    const int c = (t & 31) << 2;
    for (int r = s + (t >> 5); r < zend; r += 8)
      *(bf16x4*)&xh[r * 136 + c] =
          bf16x4{(__bf16)0.f, (__bf16)0.f, (__bf16)0.f, (__bf16)0.f};
  }
  __syncthreads();

  const int wid = t >> 6, lane = t & 63;
  const int lo16 = lane & 15, g16 = lane >> 4;

#pragma unroll
  for (int fi = 0; fi < 2; ++fi) {
    const int ft = wid + (fi << 2);
    const int feat = ft * 16 + lo16;

    f32x4 acc[4][3];   // [mtile][pool]
#pragma unroll
    for (int mt = 0; mt < 4; ++mt)
#pragma unroll
      for (int p = 0; p < 3; ++p)
        acc[mt][p] = f32x4{0.f, 0.f, 0.f, 0.f};

#pragma unroll
    for (int kt = 0; kt < 4; ++kt) {
      // slices: 0=w1j0, 1=w2j0, 2=w2j1, 3=w3j0, 4=w3j1, 5=w3j2
      bf16x8 bf[6];
#pragma unroll
      for (int sl = 0; sl < 6; ++sl)
        bf[sl] = Wpack[(((sl * 8 + ft) * 4 + kt) << 6) + lane];
#pragma unroll
      for (int mt = 0; mt < 4; ++mt) {
        if (mt < MT) {   // uniform per block
          const __bf16* ap = &xh[(mt * 16 + lo16) * 136 + kt * 32 + (g16 << 3)];
          const bf16x8 A0 = *(const bf16x8*)ap;
          const bf16x8 A1 = *(const bf16x8*)(ap + 136);
          const bf16x8 A2 = *(const bf16x8*)(ap + 272);
          acc[mt][0] = MFMA16(A0, bf[0], acc[mt][0]);
          acc[mt][1] = MFMA16(A0, bf[1], acc[mt][1]);
          acc[mt][1] = MFMA16(A1, bf[2], acc[mt][1]);
          acc[mt][2] = MFMA16(A0, bf[3], acc[mt][2]);
          acc[mt][2] = MFMA16(A1, bf[4], acc[mt][2]);
          acc[mt][2] = MFMA16(A2, bf[5], acc[mt][2]);
        }
      }
    }

    // ---- epilogue: 3-class predicate hoisting (R6 pool-3 fix) ----
    float m1 = -1e30f, m2 = -1e30f, m3 = -1e30f;
#pragma unroll
    for (int mt = 0; mt < 4; ++mt) {
      if (mt + 2 < MT) {
        // deep interior: max row = mt*16+15 <= MT*16-33+15 <= s-3 (all pools)
        const f32x4 a0 = acc[mt][0], a1 = acc[mt][1], a2 = acc[mt][2];
        m1 = fmaxf(m1, fmaxf(fmaxf(a0[0], a0[1]), fmaxf(a0[2], a0[3])));
        m2 = fmaxf(m2, fmaxf(fmaxf(a1[0], a1[1]), fmaxf(a1[2], a1[3])));
        m3 = fmaxf(m3, fmaxf(fmaxf(a2[0], a2[1]), fmaxf(a2[2], a2[3])));
      } else if (mt + 1 < MT) {
        // penultimate: max row <= s-2 -> pools 1,2 fully valid;
        // pool 3 (needs row <= s-3) keeps per-element predicates.
        const f32x4 a0 = acc[mt][0], a1 = acc[mt][1];
        m1 = fmaxf(m1, fmaxf(fmaxf(a0[0], a0[1]), fmaxf(a0[2], a0[3])));
        m2 = fmaxf(m2, fmaxf(fmaxf(a1[0], a1[1]), fmaxf(a1[2], a1[3])));
        const int base = mt * 16 + (g16 << 2);
#pragma unroll
        for (int v = 0; v < 4; ++v)
          if (base + v < s - 2) m3 = fmaxf(m3, acc[mt][2][v]);
      } else if (mt < MT) {
        // boundary tile: per-element predicates on all pools
        const int base = mt * 16 + (g16 << 2);
#pragma unroll
        for (int v = 0; v < 4; ++v) {
          const int lrow = base + v;
          if (lrow < s)     m1 = fmaxf(m1, acc[mt][0][v]);
          if (lrow < s - 1) m2 = fmaxf(m2, acc[mt][1][v]);
          if (lrow < s - 2) m3 = fmaxf(m3, acc[mt][2][v]);
        }
      }
    }
    m1 = fmaxf(m1, __shfl_xor(m1, 16)); m1 = fmaxf(m1, __shfl_xor(m1, 32));
    m2 = fmaxf(m2, __shfl_xor(m2, 16)); m2 = fmaxf(m2, __shfl_xor(m2, 32));
    m3 = fmaxf(m3, __shfl_xor(m3, 16)); m3 = fmaxf(m3, __shfl_xor(m3, 32));
    if (g16 == 0) {
      // max(relu(h)) == relu(max(Y)+b): bias row-constant, relu monotone
      const float p1 = fmaxf(m1 + cb0[feat], 0.f);
      const float p2 = fmaxf(m2 + cb1[feat], 0.f);
      const float p3 = fmaxf(m3 + cb2[feat], 0.f);
      const __bf16 h1 = (__bf16)p1, h2 = (__bf16)p2, h3 = (__bf16)p3;
      const long row = (long)b * 384;
      Phi[row + feat]       = h1;
      Plo[row + feat]       = (__bf16)(p1 - (float)h1);
      Phi[row + 128 + feat] = h2;
      Plo[row + 128 + feat] = (__bf16)(p2 - (float)h2);
      Phi[row + 256 + feat] = h3;
      Plo[row + 256 + feat] = (__bf16)(p3 - (float)h3);
    }
  }
}

// ---------------------------------------------------------------------------
// K3 v2 (proven R3): out = tanh(P[8192,384] @ lin_w^T + lin_b), split bf16
// MFMA with 3 independent chains; 1024 blocks (16 rows x 64 feats each).
// ---------------------------------------------------------------------------
__global__ __launch_bounds__(256, 4)
void k_lin(const __bf16* __restrict__ Phi, const __bf16* __restrict__ Plo,
           const bf16x8* __restrict__ Lhi, const bf16x8* __restrict__ Llo,
           const float* __restrict__ lb, float* __restrict__ out) {
  __shared__ __bf16 ph[16 * 392];   // [row][384 + 8 pad]
  __shared__ __bf16 pl[16 * 392];
  const int blk = blockIdx.x, t = threadIdx.x;
  const int mb = blk >> 1, nh = blk & 1;
  const long rbase = (long)mb * 16;
#pragma unroll
  for (int i = 0; i < 3; ++i) {
    const int ci = t + (i << 8);
    const int r = ci / 48, cc = ci % 48;
    *(int4*)&ph[r * 392 + (cc << 3)] = *(const int4*)&Phi[(rbase + r) * 384 + (cc << 3)];
    *(int4*)&pl[r * 392 + (cc << 3)] = *(const int4*)&Plo[(rbase + r) * 384 + (cc << 3)];
  }
  __syncthreads();
  const int wid = t >> 6, lane = t & 63;
  const int lo16 = lane & 15, g = lane >> 4;
  const int nt = (nh << 2) + wid;       // global n-tile 0..7
  f32x4 ahh = f32x4{0.f, 0.f, 0.f, 0.f};
  f32x4 alh = f32x4{0.f, 0.f, 0.f, 0.f};
  f32x4 ahl = f32x4{0.f, 0.f, 0.f, 0.f};
#pragma unroll
  for (int kt = 0; kt < 12; ++kt) {
    const bf16x8 bh = Lhi[((nt * 12 + kt) << 6) + lane];
    const bf16x8 bl = Llo[((nt * 12 + kt) << 6) + lane];
    const int aoff = lo16 * 392 + kt * 32 + (g << 3);
    const bf16x8 ah = *(const bf16x8*)&ph[aoff];
    const bf16x8 al = *(const bf16x8*)&pl[aoff];
    ahh = MFMA16(ah, bh, ahh);
    alh = MFMA16(al, bh, alh);
    ahl = MFMA16(ah, bl, ahl);
  }
  const int o = (nt << 4) + lo16;
  const float bias = lb[o];
#pragma unroll
  for (int v = 0; v < 4; ++v) {
    const int r = g * 4 + v;
    const float val = ahh[v] + alh[v] + ahl[v] + bias;
    out[(rbase + r) * 128 + o] = 1.f - 2.f / (__expf(2.f * val) + 1.f);
  }
}

// ---------------------------------------------------------------------------
extern "C" void kernel_launch(void* const* d_in, const int* in_sizes, int n_in,
                              void* d_out, int out_size, void* d_ws, size_t ws_size,
                              hipStream_t stream) {
  const float* x   = (const float*)d_in[0];
  const int* sizes = (const int*)d_in[1];
  const float* w0  = (const float*)d_in[2];
  const float* cb0 = (const float*)d_in[3];
  const float* w1  = (const float*)d_in[4];
  const float* cb1 = (const float*)d_in[5];
  const float* w2  = (const float*)d_in[6];
  const float* cb2 = (const float*)d_in[7];
  const float* lw  = (const float*)d_in[8];
  const float* lb  = (const float*)d_in[9];

  char* ws = (char*)d_ws;
  size_t o = 0;
  int2*   desc  = (int2*)ws;                  o += 65536;      // 8192 int2
  __bf16* Wpack = (__bf16*)(ws + o);          o += 196608;     // 48*4*64*8*2
  __bf16* Lhi   = (__bf16*)(ws + o);          o += 98304;      // 8*12*64*8*2
  __bf16* Llo   = (__bf16*)(ws + o);          o += 98304;
  __bf16* Phi   = (__bf16*)(ws + o);          o += 8192L * 384 * 2;
  __bf16* Plo   = (__bf16*)(ws + o);          o += 8192L * 384 * 2;

  k_prep<<<241, 256, 0, stream>>>(sizes, desc, w0, w1, w2, lw, Wpack, Lhi, Llo);
  k_conv<<<8192, 256, 0, stream>>>(x, desc, cb0, cb1, cb2,
                                   (const bf16x8*)Wpack, Phi, Plo);
  k_lin<<<1024, 256, 0, stream>>>(Phi, Plo, (const bf16x8*)Lhi,
                                  (const bf16x8*)Llo, lb, (float*)d_out);
}